// Round 7
// baseline (513.395 us; speedup 1.0000x reference)
//
#include <hip/hip_runtime.h>

// VQ-VAE quantize. Output must be BIT-EXACT vs numpy fp32 pipeline:
//   d_k = fl32( fl32(sumx + sume_k) - c_k ),  c_k = sequential-k FMA of (2x)&e,
//   idx = first-min argmin. (Proven in R3-R6: scalar path, absmax=0.)
//
// R7 strategy: MFMA prefilter + exact rescore.
//   s~_k = sume_k - (2x).e_k via bf16x2-split MFMA (xh*eh + xl*eh + xh*el, fp32 acc).
//   Worst-case |s~ - s_real| <= ~9e-6 (neglected terms, emb in +-1e-3, Sum|2x|<=150).
//   Reference-grid slack (two fp32 roundings @64) <= 1.6e-5. Per-row per-32k
//   supertile minima (f16 LDS table); candidate supertiles: min <= rowmin + 3e-4
//   (>=2x margin incl. 2x f16 ulp 6e-5). Rescore candidates bit-exactly, first-min.

#define N_ROWS   131072
#define NUM_EMB  1024
#define EMB_DIM  64
#define Q_ELEMS  8388608
#define THREADS  512
#define ROWS_PB  256          // 8 waves x 32 rows
#define KCHUNK   128
#define NCHUNKS  8
#define CAND_WINDOW 3.0e-4f

typedef short  short8 __attribute__((ext_vector_type(8)));
typedef float  f32x4  __attribute__((ext_vector_type(4)));

__device__ __forceinline__ unsigned short bf16_rne(float f) {
    unsigned u = __float_as_uint(f);
    u += 0x7fffu + ((u >> 16) & 1u);
    return (unsigned short)(u >> 16);
}
__device__ __forceinline__ float bf16_hi_f32(unsigned short h) {
    return __uint_as_float(((unsigned)h) << 16);
}

// numpy pairwise_sum (n=64) of fl32(a[i]*a[i]) — 8-accumulator order.
__device__ __forceinline__ float np_pairwise_sq64(const float* a) {
    #pragma clang fp contract(off)
    float r0 = a[0]*a[0], r1 = a[1]*a[1], r2 = a[2]*a[2], r3 = a[3]*a[3];
    float r4 = a[4]*a[4], r5 = a[5]*a[5], r6 = a[6]*a[6], r7 = a[7]*a[7];
    #pragma unroll
    for (int i = 8; i < 64; i += 8) {
        r0 += a[i+0]*a[i+0]; r1 += a[i+1]*a[i+1];
        r2 += a[i+2]*a[i+2]; r3 += a[i+3]*a[i+3];
        r4 += a[i+4]*a[i+4]; r5 += a[i+5]*a[i+5];
        r6 += a[i+6]*a[i+6]; r7 += a[i+7]*a[i+7];
    }
    return ((r0 + r1) + (r2 + r3)) + ((r4 + r5) + (r6 + r7));
}

// min over the 16 lanes of each DPP row via rotate-and-min (VALU pipe, no LDS).
__device__ __forceinline__ float rotmin16(float v) {
    int x;
    x = __builtin_amdgcn_update_dpp(0, __float_as_int(v), 0x121, 0xf, 0xf, true);
    v = fminf(v, __int_as_float(x));
    x = __builtin_amdgcn_update_dpp(0, __float_as_int(v), 0x122, 0xf, 0xf, true);
    v = fminf(v, __int_as_float(x));
    x = __builtin_amdgcn_update_dpp(0, __float_as_int(v), 0x124, 0xf, 0xf, true);
    v = fminf(v, __int_as_float(x));
    x = __builtin_amdgcn_update_dpp(0, __float_as_int(v), 0x128, 0xf, 0xf, true);
    v = fminf(v, __int_as_float(x));
    return v;
}

__global__ __launch_bounds__(256) void vq_prep(const float* __restrict__ emb,
                                               float* __restrict__ sume) {
    int k = blockIdx.x * 256 + threadIdx.x;
    if (k < NUM_EMB) sume[k] = np_pairwise_sq64(emb + (k << 6));
}

__global__ __launch_bounds__(THREADS, 4) void vq_mfma(const float* __restrict__ x,
                                                      const float* __restrict__ emb,
                                                      const float* __restrict__ sume_g,
                                                      float* __restrict__ out_q,
                                                      float* __restrict__ out_idx) {
    // LDS: e-chunk bf16 hi/lo [gp 0..7][krow 0..127][8], sume chunk, supertile-min table.
    __shared__ short    EH[8 * KCHUNK * 8];        // 16 KB
    __shared__ short    EL[8 * KCHUNK * 8];        // 16 KB
    __shared__ float    SUME[KCHUNK];              // 512 B
    __shared__ _Float16 TMIN[8][32][32];           // 16 KB [wave][supertile][row-in-wave]
    __shared__ int      SIDX[ROWS_PB];             // 1 KB

    const int t   = threadIdx.x;
    const int w   = t >> 6;          // wave 0..7
    const int l   = t & 63;
    const int g   = l >> 4;          // k-dim group 0..3
    const int c16 = l & 15;
    const size_t blk_row0 = (size_t)blockIdx.x * ROWS_PB;

    // ---- A-frags: 2 strips of 16 rows per wave; fold the 2.0 into x; bf16x2 split.
    // A[m][kd]: m = lane&15 (x-row), kd = 8*(lane>>4)+j. call0: dims 0-31, call1: 32-63.
    short8 ah0[2], al0[2], ah1[2], al1[2];
    #pragma unroll
    for (int s = 0; s < 2; ++s) {
        const float* xp = x + (blk_row0 + (size_t)(w*32 + s*16 + c16)) * EMB_DIM;
        #pragma unroll
        for (int j = 0; j < 8; ++j) {
            float v0 = 2.0f * xp[g*8 + j];
            unsigned short h0 = bf16_rne(v0);
            ah0[s][j] = (short)h0;
            al0[s][j] = (short)bf16_rne(v0 - bf16_hi_f32(h0));
            float v1 = 2.0f * xp[32 + g*8 + j];
            unsigned short h1 = bf16_rne(v1);
            ah1[s][j] = (short)h1;
            al1[s][j] = (short)bf16_rne(v1 - bf16_hi_f32(h1));
        }
    }

    float stash0[4], stash1[4];

    for (int c = 0; c < NCHUNKS; ++c) {
        // ---- stage e-chunk: split fp32 emb -> bf16 hi/lo into LDS (2 units/thread).
        {
            int u0   = t * 2;
            int krow = u0 >> 3;
            int gp   = u0 & 7;       // even; the pair (gp, gp+1) shares krow
            const float* src = emb + ((size_t)(c*KCHUNK + krow)) * EMB_DIM + gp*8;
            short8 h0, l0, h1, l1;
            #pragma unroll
            for (int j = 0; j < 8; ++j) {
                float e0 = src[j];
                unsigned short hh = bf16_rne(e0);
                h0[j] = (short)hh; l0[j] = (short)bf16_rne(e0 - bf16_hi_f32(hh));
                float e1 = src[8 + j];
                unsigned short h2 = bf16_rne(e1);
                h1[j] = (short)h2; l1[j] = (short)bf16_rne(e1 - bf16_hi_f32(h2));
            }
            *reinterpret_cast<short8*>(&EH[(gp    )*1024 + krow*8]) = h0;
            *reinterpret_cast<short8*>(&EH[(gp + 1)*1024 + krow*8]) = h1;
            *reinterpret_cast<short8*>(&EL[(gp    )*1024 + krow*8]) = l0;
            *reinterpret_cast<short8*>(&EL[(gp + 1)*1024 + krow*8]) = l1;
            if (t < KCHUNK) SUME[t] = sume_g[c*KCHUNK + t];
        }
        __syncthreads();

        // ---- 8 tiles of 16 k; B[kd][n]: n = lane&15 (codebook row), kd = 8*(lane>>4)+j.
        #pragma unroll
        for (int lt = 0; lt < 8; ++lt) {
            const int krow = lt*16 + c16;
            const short8 bh0 = *reinterpret_cast<const short8*>(&EH[(g    )*1024 + krow*8]);
            const short8 bh1 = *reinterpret_cast<const short8*>(&EH[(g + 4)*1024 + krow*8]);
            const short8 bl0 = *reinterpret_cast<const short8*>(&EL[(g    )*1024 + krow*8]);
            const short8 bl1 = *reinterpret_cast<const short8*>(&EL[(g + 4)*1024 + krow*8]);
            const float scol = SUME[lt*16 + c16];
            f32x4 acc0 = {0.f,0.f,0.f,0.f}, acc1 = {0.f,0.f,0.f,0.f};
            // 3 split passes x K=64 (2 calls), both strips interleaved for MFMA ILP.
            acc0 = __builtin_amdgcn_mfma_f32_16x16x32_bf16(ah0[0], bh0, acc0, 0,0,0);
            acc1 = __builtin_amdgcn_mfma_f32_16x16x32_bf16(ah0[1], bh0, acc1, 0,0,0);
            acc0 = __builtin_amdgcn_mfma_f32_16x16x32_bf16(ah1[0], bh1, acc0, 0,0,0);
            acc1 = __builtin_amdgcn_mfma_f32_16x16x32_bf16(ah1[1], bh1, acc1, 0,0,0);
            acc0 = __builtin_amdgcn_mfma_f32_16x16x32_bf16(al0[0], bh0, acc0, 0,0,0);
            acc1 = __builtin_amdgcn_mfma_f32_16x16x32_bf16(al0[1], bh0, acc1, 0,0,0);
            acc0 = __builtin_amdgcn_mfma_f32_16x16x32_bf16(al1[0], bh1, acc0, 0,0,0);
            acc1 = __builtin_amdgcn_mfma_f32_16x16x32_bf16(al1[1], bh1, acc1, 0,0,0);
            acc0 = __builtin_amdgcn_mfma_f32_16x16x32_bf16(ah0[0], bl0, acc0, 0,0,0);
            acc1 = __builtin_amdgcn_mfma_f32_16x16x32_bf16(ah0[1], bl0, acc1, 0,0,0);
            acc0 = __builtin_amdgcn_mfma_f32_16x16x32_bf16(ah1[0], bl1, acc0, 0,0,0);
            acc1 = __builtin_amdgcn_mfma_f32_16x16x32_bf16(ah1[1], bl1, acc1, 0,0,0);
            // s~ = sume - dot; per-row min over this tile's 16 cols (DPP rotate-min).
            // D[row][col]: col = lane&15, row = 4*(lane>>4)+reg.
            #pragma unroll
            for (int r = 0; r < 4; ++r) {
                float v0 = rotmin16(scol - acc0[r]);
                float v1 = rotmin16(scol - acc1[r]);
                if (lt & 1) { stash0[r] = fminf(stash0[r], v0);
                              stash1[r] = fminf(stash1[r], v1); }
                else        { stash0[r] = v0; stash1[r] = v1; }
            }
            if ((lt & 1) && c16 == 0) {           // one writer lane per group
                int st = (c*8 + lt) >> 1;          // supertile = 32 k
                #pragma unroll
                for (int r = 0; r < 4; ++r) {
                    TMIN[w][st][ 0 + 4*g + r] = (_Float16)stash0[r];
                    TMIN[w][st][16 + 4*g + r] = (_Float16)stash1[r];
                }
            }
        }
        __syncthreads();   // protect LDS before next chunk's staging
    }

    // ---- phase 2: per-row candidate supertiles -> BIT-EXACT rescore (np pipeline).
    if (t < ROWS_PB) {
        const int wid = t >> 5;
        const int rid = t & 31;
        float rmin = 3.4e38f;
        #pragma unroll
        for (int st = 0; st < 32; ++st)
            rmin = fminf(rmin, (float)TMIN[wid][st][rid]);

        float rx[EMB_DIM];
        const float4* xr = reinterpret_cast<const float4*>(x + (blk_row0 + t) * EMB_DIM);
        #pragma unroll
        for (int j = 0; j < 16; ++j) {
            float4 v = xr[j];
            rx[4*j+0] = v.x; rx[4*j+1] = v.y; rx[4*j+2] = v.z; rx[4*j+3] = v.w;
        }
        const float sumx = np_pairwise_sq64(rx);
        #pragma unroll
        for (int i = 0; i < EMB_DIM; ++i) rx[i] *= 2.0f;

        float bestd = 3.4e38f; int bestk = 0;
        for (int st = 0; st < 32; ++st) {              // ascending -> first-min
            if ((float)TMIN[wid][st][rid] <= rmin + CAND_WINDOW) {
                for (int kk = st*32; kk < st*32 + 32; ++kk) {
                    const float* e = emb + (kk << 6);
                    float cacc = 0.f;                   // sgemm sequential-k FMA order
                    #pragma unroll
                    for (int i = 0; i < EMB_DIM; ++i) cacc = fmaf(rx[i], e[i], cacc);
                    {
                        #pragma clang fp contract(off)
                        float d = (sumx + sume_g[kk]) - cacc;   // fl32 grid @ ~64
                        if (d < bestd) { bestd = d; bestk = kk; }
                    }
                }
            }
        }
        out_idx[blk_row0 + t] = (float)bestk;
        SIDX[t] = bestk;
    }
    __syncthreads();

    // ---- coalesced gather: quantized[row] = emb[idx[row]]
    const float4* emb4 = reinterpret_cast<const float4*>(emb);
    float4* q4 = reinterpret_cast<float4*>(out_q + blk_row0 * EMB_DIM);
    #pragma unroll
    for (int i = 0; i < 8; ++i) {
        int e4 = t + i * THREADS;     // 4096 float4 per block
        int rr = e4 >> 4, cc = e4 & 15;
        q4[e4] = emb4[SIDX[rr]*16 + cc];
    }
}

extern "C" void kernel_launch(void* const* d_in, const int* in_sizes, int n_in,
                              void* d_out, int out_size, void* d_ws, size_t ws_size,
                              hipStream_t stream) {
    const float* x   = (const float*)d_in[0];
    const float* emb = (const float*)d_in[1];
    float* out_q   = (float*)d_out;
    float* out_idx = out_q + Q_ELEMS;
    float* sume    = (float*)d_ws;   // 4 KB

    vq_prep<<<dim3(NUM_EMB / 256), dim3(256), 0, stream>>>(emb, sume);
    vq_mfma<<<dim3(N_ROWS / ROWS_PB), dim3(THREADS), 0, stream>>>(x, emb, sume,
                                                                  out_q, out_idx);
}

// Round 8
// 82.482 us; speedup vs baseline: 6.2243x; 6.2243x over previous
//
#include <hip/hip_runtime.h>

// VQ-VAE quantize. Output BIT-EXACT vs numpy fp32 pipeline (proven R3-R7):
//   d_k = fl32( fl32(sumx + sume_k) - c_k ), c_k = sequential-k fp32 FMA of (2x).e,
//   idx = first-minimum argmin.
//
// R8: single-pass bf16 MFMA prefilter (emb pre-converted once in prep kernel),
// two-sweep: (A) exact f32 per-row min of s~ = sume - mfma_dot; (B) recompute s~
// (deterministic) and worklist all k with s~ < RMIN + W_row, where
// W_row = SA*2^-16 + slack  (SA = sum|2x_i|; |e|<=2^-10, bf16 rel err 2^-8/side)
// rigorously covers the reference argmin. Lane-parallel exact rescore of ~1.4
// pairs/row; first-min via atomicMin(d-key) then atomicMin(k) tie-break.

#define N_ROWS   131072
#define NUM_EMB  1024
#define EMB_DIM  64
#define Q_ELEMS  8388608
#define THREADS  512
#define ROWS_PB  256          // 8 waves x 32 rows
#define KCHUNK   128
#define NCHUNKS  8
#define WCAP     2048

typedef short short8 __attribute__((ext_vector_type(8)));
typedef float f32x4  __attribute__((ext_vector_type(4)));

__device__ __forceinline__ unsigned short bf16_rne(float f) {
    unsigned u = __float_as_uint(f);
    u += 0x7fffu + ((u >> 16) & 1u);
    return (unsigned short)(u >> 16);
}

// monotone key for f32 (handles negatives): smaller float -> smaller key
__device__ __forceinline__ unsigned fkey(float d) {
    unsigned b = __float_as_uint(d);
    return b ^ (((unsigned)((int)b >> 31)) | 0x80000000u);
}

// numpy pairwise_sum (n=64) of fl32(a[i]*a[i]) — 8-accumulator order.
__device__ __forceinline__ float np_sq64(const float* a) {
    #pragma clang fp contract(off)
    float r0=a[0]*a[0],r1=a[1]*a[1],r2=a[2]*a[2],r3=a[3]*a[3];
    float r4=a[4]*a[4],r5=a[5]*a[5],r6=a[6]*a[6],r7=a[7]*a[7];
    #pragma unroll
    for (int i=8;i<64;i+=8){
        r0+=a[i+0]*a[i+0];r1+=a[i+1]*a[i+1];r2+=a[i+2]*a[i+2];r3+=a[i+3]*a[i+3];
        r4+=a[i+4]*a[i+4];r5+=a[i+5]*a[i+5];r6+=a[i+6]*a[i+6];r7+=a[i+7]*a[i+7];
    }
    return ((r0+r1)+(r2+r3))+((r4+r5)+(r6+r7));
}

// min over the 16 lanes of each DPP row (row_ror 1,2,4,8) — R7-verified.
__device__ __forceinline__ float rotmin16(float v) {
    int x;
    x = __builtin_amdgcn_update_dpp(0, __float_as_int(v), 0x121, 0xf, 0xf, true);
    v = fminf(v, __int_as_float(x));
    x = __builtin_amdgcn_update_dpp(0, __float_as_int(v), 0x122, 0xf, 0xf, true);
    v = fminf(v, __int_as_float(x));
    x = __builtin_amdgcn_update_dpp(0, __float_as_int(v), 0x124, 0xf, 0xf, true);
    v = fminf(v, __int_as_float(x));
    x = __builtin_amdgcn_update_dpp(0, __float_as_int(v), 0x128, 0xf, 0xf, true);
    v = fminf(v, __int_as_float(x));
    return v;
}

// prep: sume (np order) + emb -> bf16 in MFMA-ready layout:
// unit index = chunk*1024 + gp*128 + krow, unit = 8 bf16 (dims gp*8..gp*8+7).
__global__ __launch_bounds__(256) void vq_prep(const float* __restrict__ emb,
                                               float* __restrict__ sume,
                                               unsigned short* __restrict__ ehg) {
    int k = blockIdx.x * 256 + threadIdx.x;
    if (k < NUM_EMB) {
        sume[k] = np_sq64(emb + (k << 6));
        int c = k >> 7, krow = k & 127;
        #pragma unroll
        for (int gp = 0; gp < 8; ++gp) {
            short8 h;
            #pragma unroll
            for (int j = 0; j < 8; ++j)
                h[j] = (short)bf16_rne(emb[(k << 6) + gp*8 + j]);
            reinterpret_cast<short8*>(ehg)[c*1024 + gp*128 + krow] = h;
        }
    }
}

__global__ __launch_bounds__(THREADS, 4)
void vq_main(const float* __restrict__ x, const float* __restrict__ emb,
             const float* __restrict__ sume_g, const unsigned short* __restrict__ ehg,
             float* __restrict__ out_q, float* __restrict__ out_idx) {
    __shared__ int4     EH4[1024];        // 16KB: current bf16 e-chunk
    __shared__ float    SUME[NUM_EMB];    // 4KB
    __shared__ float    RMIN[ROWS_PB];    // exact f32 min of s~ per row
    __shared__ float    THR[ROWS_PB];
    __shared__ float    SA[ROWS_PB];      // sum |2x| per row
    __shared__ int      WL[WCAP];         // 8KB worklist (row<<10 | k)
    __shared__ float    WLD[WCAP];        // 8KB exact d per pair
    __shared__ unsigned DMIN[ROWS_PB];
    __shared__ unsigned KMIN[ROWS_PB];
    __shared__ int      SIDX[ROWS_PB];
    __shared__ unsigned WCNT;

    const int t   = threadIdx.x;
    const int w   = t >> 6;
    const int l   = t & 63;
    const int g   = l >> 4;
    const int c16 = l & 15;
    const size_t blk_row0 = (size_t)blockIdx.x * ROWS_PB;

    SUME[t]       = sume_g[t];
    SUME[t + 512] = sume_g[t + 512];

    // ---- A-frags (2 strips x 2 K-halves), fold 2.0 into x; per-row sum|2x|.
    // A[m][kd]: m = lane&15 (x-row), kd = 8*(lane>>4)+j  (R7-verified mapping).
    short8 ah[2][2];
    #pragma unroll
    for (int s = 0; s < 2; ++s) {
        const float* xp = x + (blk_row0 + (size_t)(w*32 + s*16 + c16)) * EMB_DIM;
        float sabs = 0.f;
        #pragma unroll
        for (int hf = 0; hf < 2; ++hf) {
            #pragma unroll
            for (int j = 0; j < 8; ++j) {
                float v = 2.0f * xp[hf*32 + g*8 + j];
                sabs += fabsf(v);
                ah[s][hf][j] = (short)bf16_rne(v);
            }
        }
        sabs += __shfl_xor(sabs, 16);
        sabs += __shfl_xor(sabs, 32);
        if (g == 0) SA[w*32 + s*16 + c16] = sabs;
    }

    // ---- sweep A: exact f32 running min of s~ per (strip,reg); rotmin once.
    float stash[2][4];
    #pragma unroll
    for (int s = 0; s < 2; ++s) {
        #pragma unroll
        for (int r = 0; r < 4; ++r) stash[s][r] = 3.4e38f;
    }

    for (int c = 0; c < NCHUNKS; ++c) {
        __syncthreads();
        EH4[t]       = reinterpret_cast<const int4*>(ehg)[c*1024 + t];
        EH4[t + 512] = reinterpret_cast<const int4*>(ehg)[c*1024 + t + 512];
        __syncthreads();
        #pragma unroll
        for (int lt = 0; lt < 8; ++lt) {
            const int krow = lt*16 + c16;
            short8 bh0 = reinterpret_cast<const short8*>(EH4)[(g    )*128 + krow];
            short8 bh1 = reinterpret_cast<const short8*>(EH4)[(g + 4)*128 + krow];
            float scol = SUME[c*KCHUNK + krow];
            f32x4 a0 = {0.f,0.f,0.f,0.f}, a1 = {0.f,0.f,0.f,0.f};
            a0 = __builtin_amdgcn_mfma_f32_16x16x32_bf16(ah[0][0], bh0, a0, 0,0,0);
            a1 = __builtin_amdgcn_mfma_f32_16x16x32_bf16(ah[1][0], bh0, a1, 0,0,0);
            a0 = __builtin_amdgcn_mfma_f32_16x16x32_bf16(ah[0][1], bh1, a0, 0,0,0);
            a1 = __builtin_amdgcn_mfma_f32_16x16x32_bf16(ah[1][1], bh1, a1, 0,0,0);
            #pragma unroll
            for (int r = 0; r < 4; ++r) {
                stash[0][r] = fminf(stash[0][r], scol - a0[r]);
                stash[1][r] = fminf(stash[1][r], scol - a1[r]);
            }
        }
    }
    // D-row = strip*16 + 4*g + reg (R7-verified); reduce cols via rotmin16.
    #pragma unroll
    for (int s = 0; s < 2; ++s) {
        #pragma unroll
        for (int r = 0; r < 4; ++r) {
            float v = rotmin16(stash[s][r]);
            if (c16 == 0) RMIN[w*32 + s*16 + 4*g + r] = v;
        }
    }
    __syncthreads();
    if (t < ROWS_PB) {
        // W = SA*2^-16 (two-sided bf16 product err) + grid/acc slack + margin
        THR[t]  = RMIN[t] + (SA[t] * 1.6e-5f + 4.0e-5f);
        DMIN[t] = 0xFFFFFFFFu;
        KMIN[t] = 0xFFFFFFFFu;
    }
    if (t == 0) WCNT = 0u;
    __syncthreads();

    float thrv[2][4];
    #pragma unroll
    for (int s = 0; s < 2; ++s) {
        #pragma unroll
        for (int r = 0; r < 4; ++r)
            thrv[s][r] = THR[w*32 + s*16 + 4*g + r];
    }

    // ---- sweep B: recompute s~ (bit-identical), append candidates.
    for (int c = 0; c < NCHUNKS; ++c) {
        __syncthreads();
        EH4[t]       = reinterpret_cast<const int4*>(ehg)[c*1024 + t];
        EH4[t + 512] = reinterpret_cast<const int4*>(ehg)[c*1024 + t + 512];
        __syncthreads();
        #pragma unroll
        for (int lt = 0; lt < 8; ++lt) {
            const int krow = lt*16 + c16;
            short8 bh0 = reinterpret_cast<const short8*>(EH4)[(g    )*128 + krow];
            short8 bh1 = reinterpret_cast<const short8*>(EH4)[(g + 4)*128 + krow];
            float scol = SUME[c*KCHUNK + krow];
            f32x4 a0 = {0.f,0.f,0.f,0.f}, a1 = {0.f,0.f,0.f,0.f};
            a0 = __builtin_amdgcn_mfma_f32_16x16x32_bf16(ah[0][0], bh0, a0, 0,0,0);
            a1 = __builtin_amdgcn_mfma_f32_16x16x32_bf16(ah[1][0], bh0, a1, 0,0,0);
            a0 = __builtin_amdgcn_mfma_f32_16x16x32_bf16(ah[0][1], bh1, a0, 0,0,0);
            a1 = __builtin_amdgcn_mfma_f32_16x16x32_bf16(ah[1][1], bh1, a1, 0,0,0);
            const int kk = c*KCHUNK + krow;
            #pragma unroll
            for (int r = 0; r < 4; ++r) {
                float sv0 = scol - a0[r];
                if (sv0 < thrv[0][r]) {
                    unsigned p = atomicAdd(&WCNT, 1u);
                    if (p < WCAP) WL[p] = ((w*32 + 4*g + r) << 10) | kk;
                }
                float sv1 = scol - a1[r];
                if (sv1 < thrv[1][r]) {
                    unsigned p = atomicAdd(&WCNT, 1u);
                    if (p < WCAP) WL[p] = ((w*32 + 16 + 4*g + r) << 10) | kk;
                }
            }
        }
    }
    __syncthreads();
    const unsigned wc = WCNT;

    if (wc <= WCAP) {
        // lane-parallel exact rescore: ~1.4 pairs/row expected.
        for (unsigned p = t; p < wc; p += THREADS) {
            int pr = WL[p]; int row = pr >> 10; int kk = pr & 1023;
            const float* xr = x + (blk_row0 + (size_t)row) * EMB_DIM;
            const float* er = emb + (kk << 6);
            float sumx = np_sq64(xr);
            float cc = 0.f;
            #pragma unroll 8
            for (int i = 0; i < EMB_DIM; ++i)
                cc = fmaf(2.0f * xr[i], er[i], cc);   // sgemm sequential-k order
            float d;
            {
                #pragma clang fp contract(off)
                d = (sumx + sume_g[kk]) - cc;         // fl32 grid @ ~64
            }
            WLD[p] = d;
            atomicMin(&DMIN[row], fkey(d));
        }
        __syncthreads();
        for (unsigned p = t; p < wc; p += THREADS) {
            int pr = WL[p]; int row = pr >> 10; int kk = pr & 1023;
            if (fkey(WLD[p]) == DMIN[row])
                atomicMin(&KMIN[row], (unsigned)kk);  // ties -> smallest k = first-min
        }
        __syncthreads();
        if (t < ROWS_PB) {
            int bk = (int)KMIN[t];
            SIDX[t] = bk;
            out_idx[blk_row0 + t] = (float)bk;
        }
    } else {
        // cold exact fallback (worklist overflow; never on sane data).
        if (t < ROWS_PB) {
            const float* xr = x + (blk_row0 + (size_t)t) * EMB_DIM;
            float sumx = np_sq64(xr);
            volatile const float* xv = xr;   // prevent 64-reg hoist on cold path
            float bm = 3.4e38f; int bb = 0;
            for (int kk = 0; kk < NUM_EMB; ++kk) {
                const float* er = emb + (kk << 6);
                float cc = 0.f;
                for (int i = 0; i < EMB_DIM; ++i)
                    cc = fmaf(2.0f * xv[i], er[i], cc);
                {
                    #pragma clang fp contract(off)
                    float d = (sumx + sume_g[kk]) - cc;
                    if (d < bm) { bm = d; bb = kk; }
                }
            }
            SIDX[t] = bb;
            out_idx[blk_row0 + t] = (float)bb;
        }
    }
    __syncthreads();

    // ---- coalesced gather: quantized[row] = emb[idx[row]]
    const float4* emb4 = reinterpret_cast<const float4*>(emb);
    float4* q4 = reinterpret_cast<float4*>(out_q + blk_row0 * EMB_DIM);
    #pragma unroll
    for (int i = 0; i < 8; ++i) {
        int e4 = t + i * THREADS;     // 4096 float4 per block
        int rr = e4 >> 4, cc2 = e4 & 15;
        q4[e4] = emb4[SIDX[rr]*16 + cc2];
    }
}

extern "C" void kernel_launch(void* const* d_in, const int* in_sizes, int n_in,
                              void* d_out, int out_size, void* d_ws, size_t ws_size,
                              hipStream_t stream) {
    const float* x   = (const float*)d_in[0];
    const float* emb = (const float*)d_in[1];
    float* out_q   = (float*)d_out;
    float* out_idx = out_q + Q_ELEMS;
    float*          sume = (float*)d_ws;                        // 4 KB
    unsigned short* ehg  = (unsigned short*)((char*)d_ws + 4096); // 128 KB bf16 emb

    vq_prep<<<dim3(NUM_EMB / 256), dim3(256), 0, stream>>>(emb, sume, ehg);
    vq_main<<<dim3(N_ROWS / ROWS_PB), dim3(THREADS), 0, stream>>>(x, emb, sume, ehg,
                                                                  out_q, out_idx);
}